// Round 11
// baseline (3497.503 us; speedup 1.0000x reference)
//
#include <hip/hip_runtime.h>
#include <math.h>

#define B  16
#define NN 2048
#define HH 64
#define EE 10
#define DC 66
#define HC1 16
#define HC2 2

// fp32 -> bf16 round-to-nearest-even (kept for possible bf16-out fallback)
__device__ __forceinline__ unsigned short f2bf(float f) {
    unsigned int u = __float_as_uint(f);
    u += 0x7FFFu + ((u >> 16) & 1u);
    return (unsigned short)(u >> 16);
}

// ---------------- K1: per-row tiny MLP -> nodevec [B*N,10] ----------------
__global__ __launch_bounds__(128) void k_mlp_nv(
    const float* __restrict__ x, const float* __restrict__ s2,
    const float* __restrict__ ne0,
    const float* __restrict__ w1, const float* __restrict__ b1,
    const float* __restrict__ w2, const float* __restrict__ b2,
    const float* __restrict__ w3, const float* __restrict__ b3,
    float* __restrict__ nv)
{
    __shared__ float sw1[DC*HC1];
    __shared__ float sb1[HC1];
    __shared__ float sw2[HC1*HC2];
    __shared__ float sb2[HC2];
    __shared__ float sw3[HC2*EE];
    __shared__ float sb3[EE];
    int tid = threadIdx.x;
    for (int i = tid; i < DC*HC1; i += 128) sw1[i] = w1[i];
    if (tid < HC1) sb1[tid] = b1[tid];
    if (tid < HC1*HC2) sw2[tid] = w2[tid];
    if (tid < HC2) sb2[tid] = b2[tid];
    if (tid < HC2*EE) sw3[tid] = w3[tid];
    if (tid < EE) sb3[tid] = b3[tid];
    __syncthreads();
    int row = blockIdx.x*128 + tid;        // b*N + n
    int n = row & (NN-1);
    float xs[DC];
    xs[0] = x[(size_t)row*2 + 0];
    xs[1] = x[(size_t)row*2 + 1];
    #pragma unroll
    for (int i = 0; i < HH; i++) xs[2+i] = s2[(size_t)row*HH + i];
    float h1[HC1];
    #pragma unroll
    for (int j = 0; j < HC1; j++) h1[j] = sb1[j];
    #pragma unroll
    for (int i = 0; i < DC; i++) {
        float xv = xs[i];
        #pragma unroll
        for (int j = 0; j < HC1; j++) h1[j] += xv * sw1[i*HC1 + j];
    }
    #pragma unroll
    for (int j = 0; j < HC1; j++) h1[j] = 1.f/(1.f + expf(-h1[j]));
    float h2[HC2];
    #pragma unroll
    for (int j = 0; j < HC2; j++) {
        float a = sb2[j];
        #pragma unroll
        for (int i = 0; i < HC1; i++) a += h1[i]*sw2[i*HC2 + j];
        h2[j] = 1.f/(1.f + expf(-a));
    }
    #pragma unroll
    for (int d = 0; d < EE; d++) {
        float xv = sb3[d] + h2[0]*sw3[d] + h2[1]*sw3[EE + d];
        nv[(size_t)row*EE + d] = tanhf(ne0[(size_t)n*EE + d] * xv);
    }
}

// ------------- K2 (naive): d[b,n] = rsqrt( sum_m relu(nv_n . nv_m) ) -------
__global__ __launch_bounds__(128) void k_rowsum_naive(
    const float* __restrict__ nv, float* __restrict__ dv)
{
    int b = blockIdx.y;
    int tid = threadIdx.x;
    int n = blockIdx.x*128 + tid;
    const float* nvb = nv + (size_t)b*NN*EE;
    float nva[EE];
    #pragma unroll
    for (int k = 0; k < EE; k++) nva[k] = nvb[(size_t)n*EE + k];
    __shared__ float snv[64*12];
    float acc = 0.f;
    for (int m0 = 0; m0 < NN; m0 += 64) {
        __syncthreads();
        for (int i = tid; i < 64*EE; i += 128) {
            int mm = i/EE, k = i - mm*EE;
            snv[mm*12 + k] = nvb[(size_t)m0*EE + i];
        }
        __syncthreads();
        for (int mm = 0; mm < 64; mm++) {
            float s = 0.f;
            #pragma unroll
            for (int k = 0; k < EE; k++) s += nva[k]*snv[mm*12 + k];
            acc += fmaxf(s, 0.f);
        }
    }
    dv[(size_t)b*NN + n] = 1.0f / sqrtf(acc);
}

// ------- K3 (naive): xg2[b,n,c] = d_n * sum_m relu(nv_n.nv_m)*d_m*xs[m,c] --
__global__ __launch_bounds__(128) void k_xg2_naive(
    const float* __restrict__ nv, const float* __restrict__ dv,
    const float* __restrict__ x, const float* __restrict__ s2,
    float* __restrict__ xg2)
{
    int b = blockIdx.y;
    int tid = threadIdx.x;
    int n = blockIdx.x*128 + tid;
    const float* nvb = nv + (size_t)b*NN*EE;
    float nva[EE];
    #pragma unroll
    for (int k = 0; k < EE; k++) nva[k] = nvb[(size_t)n*EE + k];
    float acc[DC];
    #pragma unroll
    for (int c = 0; c < DC; c++) acc[c] = 0.f;
    __shared__ float snv[64*12];
    __shared__ float sxs[64*68];
    __shared__ float sdm[64];
    for (int m0 = 0; m0 < NN; m0 += 64) {
        __syncthreads();
        for (int i = tid; i < 64*EE; i += 128) {
            int mm = i/EE, k = i - mm*EE;
            snv[mm*12 + k] = nvb[(size_t)m0*EE + i];
        }
        for (int i = tid; i < 64*68; i += 128) {
            int mm = i/68, c = i - mm*68;
            int m = m0 + mm;
            float v = 0.f;
            if (c < 2) v = x[((size_t)b*NN + m)*2 + c];
            else if (c < DC) v = s2[((size_t)b*NN + m)*HH + (c-2)];
            sxs[i] = v;
        }
        if (tid < 64) sdm[tid] = dv[(size_t)b*NN + m0 + tid];
        __syncthreads();
        for (int mm = 0; mm < 64; mm++) {
            float s = 0.f;
            #pragma unroll
            for (int k = 0; k < EE; k++) s += nva[k]*snv[mm*12 + k];
            float w = fmaxf(s, 0.f)*sdm[mm];
            const float* xr = &sxs[mm*68];
            #pragma unroll
            for (int c = 0; c < DC; c++) acc[c] += w*xr[c];
        }
    }
    float dn = dv[(size_t)b*NN + n];
    float* o = xg2 + ((size_t)b*NN + n)*DC;
    #pragma unroll
    for (int c = 0; c < DC; c++) o[c] = acc[c]*dn;
}

// ---- K4 (naive): per-node W = ne1@wp on the fly; one thread = one column o.
// IS_GATE: out0=zsbuf(fp32, z*state), out1=rbuf(fp32, r).
// !IS_GATE: out0=d_out (FP32 h, per reference output dtype), out1 unused.
template<int DOUT, bool IS_GATE>
__global__ __launch_bounds__(DOUT) void k_proj_naive(
    const float* __restrict__ x, const float* __restrict__ s2,
    const float* __restrict__ xg2, const float* __restrict__ ne1,
    const float* __restrict__ wp, const float* __restrict__ bp,
    const float* __restrict__ state, const float* __restrict__ rbuf,
    void* __restrict__ out0, float* __restrict__ out1)
{
    __shared__ float sxs[B*68];
    __shared__ float sxg[B*68];
    __shared__ float sne[EE];
    int tid = threadIdx.x;
    int n = blockIdx.x;
    if (tid < EE) sne[tid] = ne1[(size_t)n*EE + tid];
    for (int idx = tid; idx < B*DC; idx += DOUT) {
        int bb = idx / DC, c = idx - bb*DC;
        float xv = (c < 2) ? x[((size_t)bb*NN + n)*2 + c]
                           : s2[((size_t)bb*NN + n)*HH + (c-2)];
        sxs[bb*68 + c] = xv;
        sxg[bb*68 + c] = xg2[((size_t)bb*NN + n)*DC + c];
    }
    __syncthreads();
    int o = tid;
    float bias = 0.f;
    #pragma unroll
    for (int d = 0; d < EE; d++) bias += sne[d]*bp[d*DOUT + o];
    float a[B];
    #pragma unroll
    for (int bb = 0; bb < B; bb++) a[bb] = bias;
    for (int i = 0; i < DC; i++) {
        float w0 = 0.f, w1 = 0.f;
        #pragma unroll
        for (int d = 0; d < EE; d++) {
            w0 += sne[d]*wp[(size_t)((d*2+0)*DC + i)*DOUT + o];
            w1 += sne[d]*wp[(size_t)((d*2+1)*DC + i)*DOUT + o];
        }
        #pragma unroll
        for (int bb = 0; bb < B; bb++)
            a[bb] += sxs[bb*68 + i]*w0 + sxg[bb*68 + i]*w1;
    }
    if constexpr (IS_GATE) {
        float* zs = (float*)out0;
        #pragma unroll
        for (int bb = 0; bb < B; bb++) {
            float sig = 1.f/(1.f + expf(-a[bb]));
            size_t off = ((size_t)bb*NN + n)*HH;
            if (o < HH) zs[off + o] = sig * state[off + o];
            else        out1[off + o - HH] = sig;
        }
    } else {
        float* ob = (float*)out0;
        #pragma unroll
        for (int bb = 0; bb < B; bb++) {
            size_t off = ((size_t)bb*NN + n)*HH;
            float rr = rbuf[off + o];
            float st = state[off + o];
            float hc = tanhf(a[bb]);
            ob[off + o] = rr*st + (1.f - rr)*hc;
        }
    }
}

extern "C" void kernel_launch(void* const* d_in, const int* in_sizes, int n_in,
                              void* d_out, int out_size, void* d_ws, size_t ws_size,
                              hipStream_t stream)
{
    (void)in_sizes; (void)n_in; (void)out_size; (void)ws_size;
    const float* x   = (const float*)d_in[0];
    const float* st  = (const float*)d_in[1];
    const float* ne0 = (const float*)d_in[2];
    const float* ne1 = (const float*)d_in[3];
    const float* gwp = (const float*)d_in[4];
    const float* gbp = (const float*)d_in[5];
    const float* gw1 = (const float*)d_in[6];
    const float* gb1 = (const float*)d_in[7];
    const float* gw2 = (const float*)d_in[8];
    const float* gb2 = (const float*)d_in[9];
    const float* gw3 = (const float*)d_in[10];
    const float* gb3 = (const float*)d_in[11];
    const float* uwp = (const float*)d_in[12];
    const float* ubp = (const float*)d_in[13];
    const float* uw1 = (const float*)d_in[14];
    const float* ub1 = (const float*)d_in[15];
    const float* uw2 = (const float*)d_in[16];
    const float* ub2 = (const float*)d_in[17];
    const float* uw3 = (const float*)d_in[18];
    const float* ub3 = (const float*)d_in[19];

    float* ws    = (float*)d_ws;
    float* nvbuf = ws;                                   // B*N*E  =   327,680
    float* dvbuf = nvbuf + (size_t)B*NN*EE;              // B*N    =    32,768
    float* xg2   = dvbuf + (size_t)B*NN;                 // B*N*66 = 2,162,688
    float* zsbuf = xg2 + (size_t)B*NN*DC;                // B*N*64 = 2,097,152
    float* rbuf  = zsbuf + (size_t)B*NN*HH;              // B*N*64 = 2,097,152
    // total 6,717,440 floats = 26.9 MB

    // ---- gate GCN: z_r = sigmoid(gcn(concat(x,state))) ----
    k_mlp_nv<<<dim3((B*NN)/128), dim3(128), 0, stream>>>(x, st, ne0, gw1, gb1, gw2, gb2, gw3, gb3, nvbuf);
    k_rowsum_naive<<<dim3(NN/128, B), dim3(128), 0, stream>>>(nvbuf, dvbuf);
    k_xg2_naive<<<dim3(NN/128, B), dim3(128), 0, stream>>>(nvbuf, dvbuf, x, st, xg2);
    k_proj_naive<128,true><<<dim3(NN), dim3(128), 0, stream>>>(x, st, xg2, ne1, gwp, gbp, st, st, (void*)zsbuf, rbuf);
    // ---- update GCN on concat(x, z*state); h = r*state + (1-r)*tanh(...) ----
    k_mlp_nv<<<dim3((B*NN)/128), dim3(128), 0, stream>>>(x, zsbuf, ne0, uw1, ub1, uw2, ub2, uw3, ub3, nvbuf);
    k_rowsum_naive<<<dim3(NN/128, B), dim3(128), 0, stream>>>(nvbuf, dvbuf);
    k_xg2_naive<<<dim3(NN/128, B), dim3(128), 0, stream>>>(nvbuf, dvbuf, x, zsbuf, xg2);
    k_proj_naive<64,false><<<dim3(NN), dim3(64), 0, stream>>>(x, zsbuf, xg2, ne1, uwp, ubp, st, rbuf, d_out, rbuf);
}

// Round 12
// 1214.136 us; speedup vs baseline: 2.8807x; 2.8807x over previous
//
#include <hip/hip_runtime.h>
#include <math.h>

#define B  16
#define NN 2048
#define HH 64
#define EE 10
#define DC 66
#define HC1 16
#define HC2 2
#define ZSPLIT 2

// ---------------- K1: per-row tiny MLP -> nodevec [B*N,10] ----------------
__global__ __launch_bounds__(128) void k_mlp_nv(
    const float* __restrict__ x, const float* __restrict__ s2,
    const float* __restrict__ ne0,
    const float* __restrict__ w1, const float* __restrict__ b1,
    const float* __restrict__ w2, const float* __restrict__ b2,
    const float* __restrict__ w3, const float* __restrict__ b3,
    float* __restrict__ nv)
{
    __shared__ float sw1[DC*HC1];
    __shared__ float sb1[HC1];
    __shared__ float sw2[HC1*HC2];
    __shared__ float sb2[HC2];
    __shared__ float sw3[HC2*EE];
    __shared__ float sb3[EE];
    int tid = threadIdx.x;
    for (int i = tid; i < DC*HC1; i += 128) sw1[i] = w1[i];
    if (tid < HC1) sb1[tid] = b1[tid];
    if (tid < HC1*HC2) sw2[tid] = w2[tid];
    if (tid < HC2) sb2[tid] = b2[tid];
    if (tid < HC2*EE) sw3[tid] = w3[tid];
    if (tid < EE) sb3[tid] = b3[tid];
    __syncthreads();
    int row = blockIdx.x*128 + tid;        // b*N + n
    int n = row & (NN-1);
    float xs[DC];
    xs[0] = x[(size_t)row*2 + 0];
    xs[1] = x[(size_t)row*2 + 1];
    #pragma unroll
    for (int i = 0; i < HH; i++) xs[2+i] = s2[(size_t)row*HH + i];
    float h1[HC1];
    #pragma unroll
    for (int j = 0; j < HC1; j++) h1[j] = sb1[j];
    #pragma unroll
    for (int i = 0; i < DC; i++) {
        float xv = xs[i];
        #pragma unroll
        for (int j = 0; j < HC1; j++) h1[j] += xv * sw1[i*HC1 + j];
    }
    #pragma unroll
    for (int j = 0; j < HC1; j++) h1[j] = 1.f/(1.f + expf(-h1[j]));
    float h2[HC2];
    #pragma unroll
    for (int j = 0; j < HC2; j++) {
        float a = sb2[j];
        #pragma unroll
        for (int i = 0; i < HC1; i++) a += h1[i]*sw2[i*HC2 + j];
        h2[j] = 1.f/(1.f + expf(-a));
    }
    #pragma unroll
    for (int d = 0; d < EE; d++) {
        float xv = sb3[d] + h2[0]*sw3[d] + h2[1]*sw3[EE + d];
        nv[(size_t)row*EE + d] = tanhf(ne0[(size_t)n*EE + d] * xv);
    }
}

// ------------- K2 (naive): d[b,n] = rsqrt( sum_m relu(nv_n . nv_m) ) -------
__global__ __launch_bounds__(128) void k_rowsum_naive(
    const float* __restrict__ nv, float* __restrict__ dv)
{
    int b = blockIdx.y;
    int tid = threadIdx.x;
    int n = blockIdx.x*128 + tid;
    const float* nvb = nv + (size_t)b*NN*EE;
    float nva[EE];
    #pragma unroll
    for (int k = 0; k < EE; k++) nva[k] = nvb[(size_t)n*EE + k];
    __shared__ float snv[64*12];
    float acc = 0.f;
    for (int m0 = 0; m0 < NN; m0 += 64) {
        __syncthreads();
        for (int i = tid; i < 64*EE; i += 128) {
            int mm = i/EE, k = i - mm*EE;
            snv[mm*12 + k] = nvb[(size_t)m0*EE + i];
        }
        __syncthreads();
        for (int mm = 0; mm < 64; mm++) {
            float s = 0.f;
            #pragma unroll
            for (int k = 0; k < EE; k++) s += nva[k]*snv[mm*12 + k];
            acc += fmaxf(s, 0.f);
        }
    }
    dv[(size_t)b*NN + n] = 1.0f / sqrtf(acc);
}

// ---- K3 (opt): x_g2 partials; 512 thr = 2 chan-groups x 256 rows; m-split.
// Wave-group g = tid>>8 owns channels [32g,32g+32) (+ ch 64,65 on g=1).
// Partial layout: [z][b][c][n], stores n-coalesced. Summed in k_proj staging.
__global__ __launch_bounds__(512) void k_xg2_opt(
    const float* __restrict__ nv, const float* __restrict__ dv,
    const float* __restrict__ x, const float* __restrict__ s2,
    float* __restrict__ xg2p)
{
    int b = blockIdx.y;
    int z = blockIdx.z;
    int tid = threadIdx.x;
    int g = tid >> 8;                      // channel group (wave-uniform)
    int r = tid & 255;
    int n = blockIdx.x*256 + r;
    const float* nvb = nv + (size_t)b*NN*EE;
    float nva[EE];
    #pragma unroll
    for (int k = 0; k < EE; k++) nva[k] = nvb[(size_t)n*EE + k];
    float acc[32];
    float accx0 = 0.f, accx1 = 0.f;        // ch 64,65 (g=1 only)
    #pragma unroll
    for (int c = 0; c < 32; c++) acc[c] = 0.f;
    __shared__ __align__(16) float snv[64*12];
    __shared__ __align__(16) float sxs[64*68];
    __shared__ float sdm[64];
    int mbeg = z*(NN/ZSPLIT);
    for (int m0 = mbeg; m0 < mbeg + NN/ZSPLIT; m0 += 64) {
        __syncthreads();
        for (int i = tid; i < 64*EE; i += 512) {
            int mm = i/EE, k = i - mm*EE;
            snv[mm*12 + k] = nvb[(size_t)m0*EE + i];
        }
        for (int i = tid; i < 64*68; i += 512) {
            int mm = i/68, c = i - mm*68;
            int m = m0 + mm;
            float v = 0.f;
            if (c < 2) v = x[((size_t)b*NN + m)*2 + c];
            else if (c < DC) v = s2[((size_t)b*NN + m)*HH + (c-2)];
            sxs[i] = v;
        }
        if (tid < 64) sdm[tid] = dv[(size_t)b*NN + m0 + tid];
        __syncthreads();
        #pragma unroll 2
        for (int mm = 0; mm < 64; mm++) {
            const float4* nv4 = (const float4*)&snv[mm*12];
            float4 q0 = nv4[0], q1 = nv4[1];
            float2 q2 = *(const float2*)&snv[mm*12 + 8];
            float s = nva[0]*q0.x + nva[1]*q0.y + nva[2]*q0.z + nva[3]*q0.w
                    + nva[4]*q1.x + nva[5]*q1.y + nva[6]*q1.z + nva[7]*q1.w
                    + nva[8]*q2.x + nva[9]*q2.y;
            float w = fmaxf(s, 0.f)*sdm[mm];
            const float4* x4 = (const float4*)&sxs[mm*68 + (g<<5)];
            #pragma unroll
            for (int j = 0; j < 8; j++) {
                float4 v = x4[j];
                acc[4*j+0] += w*v.x; acc[4*j+1] += w*v.y;
                acc[4*j+2] += w*v.z; acc[4*j+3] += w*v.w;
            }
            if (g) {
                float2 xe = *(const float2*)&sxs[mm*68 + 64];
                accx0 += w*xe.x; accx1 += w*xe.y;
            }
        }
    }
    float dn = dv[(size_t)b*NN + n];
    float* outz = xg2p + ((size_t)z*B + b)*(size_t)DC*NN;
    int cbase = g << 5;
    #pragma unroll
    for (int c = 0; c < 32; c++)
        outz[(size_t)(cbase+c)*NN + n] = acc[c]*dn;
    if (g) {
        outz[(size_t)64*NN + n] = accx0*dn;
        outz[(size_t)65*NN + n] = accx1*dn;
    }
}

// ---- K4 (naive): per-node W = ne1@wp on the fly; one thread = one column o.
// sxg staging sums the ZSPLIT m-partials from [z][b][c][n] layout.
// IS_GATE: out0=zsbuf(fp32, z*state), out1=rbuf(fp32, r).
// !IS_GATE: out0=d_out (fp32 h), out1 unused.
template<int DOUT, bool IS_GATE>
__global__ __launch_bounds__(DOUT) void k_proj_naive(
    const float* __restrict__ x, const float* __restrict__ s2,
    const float* __restrict__ xg2p, const float* __restrict__ ne1,
    const float* __restrict__ wp, const float* __restrict__ bp,
    const float* __restrict__ state, const float* __restrict__ rbuf,
    void* __restrict__ out0, float* __restrict__ out1)
{
    __shared__ float sxs[B*68];
    __shared__ float sxg[B*68];
    __shared__ float sne[EE];
    int tid = threadIdx.x;
    int n = blockIdx.x;
    if (tid < EE) sne[tid] = ne1[(size_t)n*EE + tid];
    for (int idx = tid; idx < B*DC; idx += DOUT) {
        int bb = idx / DC, c = idx - bb*DC;
        float xv = (c < 2) ? x[((size_t)bb*NN + n)*2 + c]
                           : s2[((size_t)bb*NN + n)*HH + (c-2)];
        sxs[bb*68 + c] = xv;
        const float* qp = xg2p + ((size_t)bb*DC + c)*NN + n;
        sxg[bb*68 + c] = qp[0] + qp[(size_t)B*DC*NN];   // sum ZSPLIT=2 partials
    }
    __syncthreads();
    int o = tid;
    float bias = 0.f;
    #pragma unroll
    for (int d = 0; d < EE; d++) bias += sne[d]*bp[d*DOUT + o];
    float a[B];
    #pragma unroll
    for (int bb = 0; bb < B; bb++) a[bb] = bias;
    for (int i = 0; i < DC; i++) {
        float w0 = 0.f, w1 = 0.f;
        #pragma unroll
        for (int d = 0; d < EE; d++) {
            w0 += sne[d]*wp[(size_t)((d*2+0)*DC + i)*DOUT + o];
            w1 += sne[d]*wp[(size_t)((d*2+1)*DC + i)*DOUT + o];
        }
        #pragma unroll
        for (int bb = 0; bb < B; bb++)
            a[bb] += sxs[bb*68 + i]*w0 + sxg[bb*68 + i]*w1;
    }
    if constexpr (IS_GATE) {
        float* zs = (float*)out0;
        #pragma unroll
        for (int bb = 0; bb < B; bb++) {
            float sig = 1.f/(1.f + expf(-a[bb]));
            size_t off = ((size_t)bb*NN + n)*HH;
            if (o < HH) zs[off + o] = sig * state[off + o];
            else        out1[off + o - HH] = sig;
        }
    } else {
        float* ob = (float*)out0;
        #pragma unroll
        for (int bb = 0; bb < B; bb++) {
            size_t off = ((size_t)bb*NN + n)*HH;
            float rr = rbuf[off + o];
            float st = state[off + o];
            float hc = tanhf(a[bb]);
            ob[off + o] = rr*st + (1.f - rr)*hc;
        }
    }
}

extern "C" void kernel_launch(void* const* d_in, const int* in_sizes, int n_in,
                              void* d_out, int out_size, void* d_ws, size_t ws_size,
                              hipStream_t stream)
{
    (void)in_sizes; (void)n_in; (void)out_size; (void)ws_size;
    const float* x   = (const float*)d_in[0];
    const float* st  = (const float*)d_in[1];
    const float* ne0 = (const float*)d_in[2];
    const float* ne1 = (const float*)d_in[3];
    const float* gwp = (const float*)d_in[4];
    const float* gbp = (const float*)d_in[5];
    const float* gw1 = (const float*)d_in[6];
    const float* gb1 = (const float*)d_in[7];
    const float* gw2 = (const float*)d_in[8];
    const float* gb2 = (const float*)d_in[9];
    const float* gw3 = (const float*)d_in[10];
    const float* gb3 = (const float*)d_in[11];
    const float* uwp = (const float*)d_in[12];
    const float* ubp = (const float*)d_in[13];
    const float* uw1 = (const float*)d_in[14];
    const float* ub1 = (const float*)d_in[15];
    const float* uw2 = (const float*)d_in[16];
    const float* ub2 = (const float*)d_in[17];
    const float* uw3 = (const float*)d_in[18];
    const float* ub3 = (const float*)d_in[19];

    float* ws    = (float*)d_ws;
    float* nvbuf = ws;                                   // B*N*E          =   327,680
    float* dvbuf = nvbuf + (size_t)B*NN*EE;              // B*N            =    32,768
    float* xg2p  = dvbuf + (size_t)B*NN;                 // ZSPLIT*B*66*N  = 4,325,376
    float* zsbuf = xg2p + (size_t)ZSPLIT*B*DC*NN;        // B*N*64         = 2,097,152
    float* rbuf  = zsbuf + (size_t)B*NN*HH;              // B*N*64         = 2,097,152
    // total 8,880,128 floats = 35.5 MB

    // ---- gate GCN: z_r = sigmoid(gcn(concat(x,state))) ----
    k_mlp_nv<<<dim3((B*NN)/128), dim3(128), 0, stream>>>(x, st, ne0, gw1, gb1, gw2, gb2, gw3, gb3, nvbuf);
    k_rowsum_naive<<<dim3(NN/128, B), dim3(128), 0, stream>>>(nvbuf, dvbuf);
    k_xg2_opt<<<dim3(NN/256, B, ZSPLIT), dim3(512), 0, stream>>>(nvbuf, dvbuf, x, st, xg2p);
    k_proj_naive<128,true><<<dim3(NN), dim3(128), 0, stream>>>(x, st, xg2p, ne1, gwp, gbp, st, st, (void*)zsbuf, rbuf);
    // ---- update GCN on concat(x, z*state); h = r*state + (1-r)*tanh(...) ----
    k_mlp_nv<<<dim3((B*NN)/128), dim3(128), 0, stream>>>(x, zsbuf, ne0, uw1, ub1, uw2, ub2, uw3, ub3, nvbuf);
    k_rowsum_naive<<<dim3(NN/128, B), dim3(128), 0, stream>>>(nvbuf, dvbuf);
    k_xg2_opt<<<dim3(NN/256, B, ZSPLIT), dim3(512), 0, stream>>>(nvbuf, dvbuf, x, zsbuf, xg2p);
    k_proj_naive<64,false><<<dim3(NN), dim3(64), 0, stream>>>(x, zsbuf, xg2p, ne1, uwp, ubp, st, rbuf, d_out, rbuf);
}

// Round 13
// 842.837 us; speedup vs baseline: 4.1497x; 1.4405x over previous
//
#include <hip/hip_runtime.h>
#include <math.h>

#define B  16
#define NN 2048
#define HH 64
#define EE 10
#define DC 66
#define HC1 16
#define HC2 2
#define ZSPLIT 4

// ---------------- K1: per-row tiny MLP -> nodevec [B*N,10] ----------------
__global__ __launch_bounds__(128) void k_mlp_nv(
    const float* __restrict__ x, const float* __restrict__ s2,
    const float* __restrict__ ne0,
    const float* __restrict__ w1, const float* __restrict__ b1,
    const float* __restrict__ w2, const float* __restrict__ b2,
    const float* __restrict__ w3, const float* __restrict__ b3,
    float* __restrict__ nv)
{
    __shared__ float sw1[DC*HC1];
    __shared__ float sb1[HC1];
    __shared__ float sw2[HC1*HC2];
    __shared__ float sb2[HC2];
    __shared__ float sw3[HC2*EE];
    __shared__ float sb3[EE];
    int tid = threadIdx.x;
    for (int i = tid; i < DC*HC1; i += 128) sw1[i] = w1[i];
    if (tid < HC1) sb1[tid] = b1[tid];
    if (tid < HC1*HC2) sw2[tid] = w2[tid];
    if (tid < HC2) sb2[tid] = b2[tid];
    if (tid < HC2*EE) sw3[tid] = w3[tid];
    if (tid < EE) sb3[tid] = b3[tid];
    __syncthreads();
    int row = blockIdx.x*128 + tid;        // b*N + n
    int n = row & (NN-1);
    float xs[DC];
    xs[0] = x[(size_t)row*2 + 0];
    xs[1] = x[(size_t)row*2 + 1];
    #pragma unroll
    for (int i = 0; i < HH; i++) xs[2+i] = s2[(size_t)row*HH + i];
    float h1[HC1];
    #pragma unroll
    for (int j = 0; j < HC1; j++) h1[j] = sb1[j];
    #pragma unroll
    for (int i = 0; i < DC; i++) {
        float xv = xs[i];
        #pragma unroll
        for (int j = 0; j < HC1; j++) h1[j] += xv * sw1[i*HC1 + j];
    }
    #pragma unroll
    for (int j = 0; j < HC1; j++) h1[j] = 1.f/(1.f + expf(-h1[j]));
    float h2[HC2];
    #pragma unroll
    for (int j = 0; j < HC2; j++) {
        float a = sb2[j];
        #pragma unroll
        for (int i = 0; i < HC1; i++) a += h1[i]*sw2[i*HC2 + j];
        h2[j] = 1.f/(1.f + expf(-a));
    }
    #pragma unroll
    for (int d = 0; d < EE; d++) {
        float xv = sb3[d] + h2[0]*sw3[d] + h2[1]*sw3[EE + d];
        nv[(size_t)row*EE + d] = tanhf(ne0[(size_t)n*EE + d] * xv);
    }
}

// -- K2: d[b,n] = rsqrt(sum_m relu(nv_n.nv_m)); 512 thr = 4 m-groups x 128 n.
__global__ __launch_bounds__(512) void k_rowsum2(
    const float* __restrict__ nv, float* __restrict__ dv)
{
    int b = blockIdx.y;
    int tid = threadIdx.x;
    int q = tid >> 7;          // m-group 0..3
    int t = tid & 127;         // row lane
    int n = blockIdx.x*128 + t;
    const float* nvb = nv + (size_t)b*NN*EE;
    float nva[EE];
    #pragma unroll
    for (int k = 0; k < EE; k++) nva[k] = nvb[(size_t)n*EE + k];
    __shared__ float snv[4][64*12];
    __shared__ float sp[512];
    float acc = 0.f;
    for (int ot = 0; ot < 8; ot++) {
        int m0 = q*512 + ot*64;
        __syncthreads();
        for (int i = t; i < 64*EE; i += 128) {
            int mm = i/EE, k = i - mm*EE;
            snv[q][mm*12 + k] = nvb[(size_t)m0*EE + i];
        }
        __syncthreads();
        for (int mm = 0; mm < 64; mm++) {
            const float* qv = &snv[q][mm*12];
            float s = 0.f;
            #pragma unroll
            for (int k = 0; k < EE; k++) s += nva[k]*qv[k];
            acc += fmaxf(s, 0.f);
        }
    }
    sp[tid] = acc;
    __syncthreads();
    if (tid < 128) {
        float r = sp[tid] + sp[128+tid] + sp[256+tid] + sp[384+tid];
        dv[(size_t)b*NN + blockIdx.x*128 + tid] = 1.0f / sqrtf(r);
    }
}

// ---- K3: x_g2 partial over m-range z; 512 thr = 2 chan-groups x 256 rows.
// Accumulates dn-scaled partials into xg2[b][c][n] via fp32 atomics
// (buffer zeroed by hipMemsetAsync before launch).
__global__ __launch_bounds__(512) void k_xg2_opt(
    const float* __restrict__ nv, const float* __restrict__ dv,
    const float* __restrict__ x, const float* __restrict__ s2,
    float* __restrict__ xg2)
{
    int b = blockIdx.y;
    int z = blockIdx.z;
    int tid = threadIdx.x;
    int g = tid >> 8;                      // channel group (wave-uniform)
    int r = tid & 255;
    int n = blockIdx.x*256 + r;
    const float* nvb = nv + (size_t)b*NN*EE;
    float nva[EE];
    #pragma unroll
    for (int k = 0; k < EE; k++) nva[k] = nvb[(size_t)n*EE + k];
    float acc[32];
    float accx0 = 0.f, accx1 = 0.f;        // ch 64,65 (g=1 only)
    #pragma unroll
    for (int c = 0; c < 32; c++) acc[c] = 0.f;
    __shared__ __align__(16) float snv[64*12];
    __shared__ __align__(16) float sxs[64*68];
    __shared__ float sdm[64];
    int mbeg = z*(NN/ZSPLIT);
    for (int m0 = mbeg; m0 < mbeg + NN/ZSPLIT; m0 += 64) {
        __syncthreads();
        for (int i = tid; i < 64*EE; i += 512) {
            int mm = i/EE, k = i - mm*EE;
            snv[mm*12 + k] = nvb[(size_t)m0*EE + i];
        }
        for (int i = tid; i < 64*68; i += 512) {
            int mm = i/68, c = i - mm*68;
            int m = m0 + mm;
            float v = 0.f;
            if (c < 2) v = x[((size_t)b*NN + m)*2 + c];
            else if (c < DC) v = s2[((size_t)b*NN + m)*HH + (c-2)];
            sxs[i] = v;
        }
        if (tid < 64) sdm[tid] = dv[(size_t)b*NN + m0 + tid];
        __syncthreads();
        #pragma unroll 2
        for (int mm = 0; mm < 64; mm++) {
            const float4* nv4 = (const float4*)&snv[mm*12];
            float4 q0 = nv4[0], q1 = nv4[1];
            float2 q2 = *(const float2*)&snv[mm*12 + 8];
            float s = nva[0]*q0.x + nva[1]*q0.y + nva[2]*q0.z + nva[3]*q0.w
                    + nva[4]*q1.x + nva[5]*q1.y + nva[6]*q1.z + nva[7]*q1.w
                    + nva[8]*q2.x + nva[9]*q2.y;
            float w = fmaxf(s, 0.f)*sdm[mm];
            const float4* x4 = (const float4*)&sxs[mm*68 + (g<<5)];
            #pragma unroll
            for (int j = 0; j < 8; j++) {
                float4 v = x4[j];
                acc[4*j+0] += w*v.x; acc[4*j+1] += w*v.y;
                acc[4*j+2] += w*v.z; acc[4*j+3] += w*v.w;
            }
            if (g) {
                float2 xe = *(const float2*)&sxs[mm*68 + 64];
                accx0 += w*xe.x; accx1 += w*xe.y;
            }
        }
    }
    float dn = dv[(size_t)b*NN + n];
    float* outb = xg2 + (size_t)b*DC*NN;
    int cbase = g << 5;
    #pragma unroll
    for (int c = 0; c < 32; c++)
        unsafeAtomicAdd(&outb[(size_t)(cbase+c)*NN + n], acc[c]*dn);
    if (g) {
        unsafeAtomicAdd(&outb[(size_t)64*NN + n], accx0*dn);
        unsafeAtomicAdd(&outb[(size_t)65*NN + n], accx1*dn);
    }
}

// ---- K4: per-node W = ne1@wp on the fly; one thread = one column o.
// xg2 layout [b][c][n]. IS_GATE: out0=zsbuf(fp32), out1=rbuf(fp32, r).
// !IS_GATE: out0=d_out (fp32 h), out1 unused.
template<int DOUT, bool IS_GATE>
__global__ __launch_bounds__(DOUT) void k_proj_naive(
    const float* __restrict__ x, const float* __restrict__ s2,
    const float* __restrict__ xg2, const float* __restrict__ ne1,
    const float* __restrict__ wp, const float* __restrict__ bp,
    const float* __restrict__ state, const float* __restrict__ rbuf,
    void* __restrict__ out0, float* __restrict__ out1)
{
    __shared__ float sxs[B*68];
    __shared__ float sxg[B*68];
    __shared__ float sne[EE];
    int tid = threadIdx.x;
    int n = blockIdx.x;
    if (tid < EE) sne[tid] = ne1[(size_t)n*EE + tid];
    for (int idx = tid; idx < B*DC; idx += DOUT) {
        int bb = idx / DC, c = idx - bb*DC;
        float xv = (c < 2) ? x[((size_t)bb*NN + n)*2 + c]
                           : s2[((size_t)bb*NN + n)*HH + (c-2)];
        sxs[bb*68 + c] = xv;
        sxg[bb*68 + c] = xg2[((size_t)bb*DC + c)*NN + n];
    }
    __syncthreads();
    int o = tid;
    float bias = 0.f;
    #pragma unroll
    for (int d = 0; d < EE; d++) bias += sne[d]*bp[d*DOUT + o];
    float a[B];
    #pragma unroll
    for (int bb = 0; bb < B; bb++) a[bb] = bias;
    for (int i = 0; i < DC; i++) {
        float w0 = 0.f, w1 = 0.f;
        #pragma unroll
        for (int d = 0; d < EE; d++) {
            w0 += sne[d]*wp[(size_t)((d*2+0)*DC + i)*DOUT + o];
            w1 += sne[d]*wp[(size_t)((d*2+1)*DC + i)*DOUT + o];
        }
        #pragma unroll
        for (int bb = 0; bb < B; bb++)
            a[bb] += sxs[bb*68 + i]*w0 + sxg[bb*68 + i]*w1;
    }
    if constexpr (IS_GATE) {
        float* zs = (float*)out0;
        #pragma unroll
        for (int bb = 0; bb < B; bb++) {
            float sig = 1.f/(1.f + expf(-a[bb]));
            size_t off = ((size_t)bb*NN + n)*HH;
            if (o < HH) zs[off + o] = sig * state[off + o];
            else        out1[off + o - HH] = sig;
        }
    } else {
        float* ob = (float*)out0;
        #pragma unroll
        for (int bb = 0; bb < B; bb++) {
            size_t off = ((size_t)bb*NN + n)*HH;
            float rr = rbuf[off + o];
            float st = state[off + o];
            float hc = tanhf(a[bb]);
            ob[off + o] = rr*st + (1.f - rr)*hc;
        }
    }
}

extern "C" void kernel_launch(void* const* d_in, const int* in_sizes, int n_in,
                              void* d_out, int out_size, void* d_ws, size_t ws_size,
                              hipStream_t stream)
{
    (void)in_sizes; (void)n_in; (void)out_size; (void)ws_size;
    const float* x   = (const float*)d_in[0];
    const float* st  = (const float*)d_in[1];
    const float* ne0 = (const float*)d_in[2];
    const float* ne1 = (const float*)d_in[3];
    const float* gwp = (const float*)d_in[4];
    const float* gbp = (const float*)d_in[5];
    const float* gw1 = (const float*)d_in[6];
    const float* gb1 = (const float*)d_in[7];
    const float* gw2 = (const float*)d_in[8];
    const float* gb2 = (const float*)d_in[9];
    const float* gw3 = (const float*)d_in[10];
    const float* gb3 = (const float*)d_in[11];
    const float* uwp = (const float*)d_in[12];
    const float* ubp = (const float*)d_in[13];
    const float* uw1 = (const float*)d_in[14];
    const float* ub1 = (const float*)d_in[15];
    const float* uw2 = (const float*)d_in[16];
    const float* ub2 = (const float*)d_in[17];
    const float* uw3 = (const float*)d_in[18];
    const float* ub3 = (const float*)d_in[19];

    float* ws    = (float*)d_ws;
    float* nvbuf = ws;                                   // B*N*E  =   327,680
    float* dvbuf = nvbuf + (size_t)B*NN*EE;              // B*N    =    32,768
    float* xg2   = dvbuf + (size_t)B*NN;                 // B*66*N = 2,162,688
    float* zsbuf = xg2 + (size_t)B*DC*NN;                // B*N*64 = 2,097,152
    float* rbuf  = zsbuf + (size_t)B*NN*HH;              // B*N*64 = 2,097,152
    // total 6,717,440 floats = 26.9 MB

    const size_t xg2_bytes = (size_t)B*DC*NN*sizeof(float);

    // ---- gate GCN: z_r = sigmoid(gcn(concat(x,state))) ----
    k_mlp_nv<<<dim3((B*NN)/128), dim3(128), 0, stream>>>(x, st, ne0, gw1, gb1, gw2, gb2, gw3, gb3, nvbuf);
    k_rowsum2<<<dim3(NN/128, B), dim3(512), 0, stream>>>(nvbuf, dvbuf);
    hipMemsetAsync(xg2, 0, xg2_bytes, stream);
    k_xg2_opt<<<dim3(NN/256, B, ZSPLIT), dim3(512), 0, stream>>>(nvbuf, dvbuf, x, st, xg2);
    k_proj_naive<128,true><<<dim3(NN), dim3(128), 0, stream>>>(x, st, xg2, ne1, gwp, gbp, st, st, (void*)zsbuf, rbuf);
    // ---- update GCN on concat(x, z*state); h = r*state + (1-r)*tanh(...) ----
    k_mlp_nv<<<dim3((B*NN)/128), dim3(128), 0, stream>>>(x, zsbuf, ne0, uw1, ub1, uw2, ub2, uw3, ub3, nvbuf);
    k_rowsum2<<<dim3(NN/128, B), dim3(512), 0, stream>>>(nvbuf, dvbuf);
    hipMemsetAsync(xg2, 0, xg2_bytes, stream);
    k_xg2_opt<<<dim3(NN/256, B, ZSPLIT), dim3(512), 0, stream>>>(nvbuf, dvbuf, x, zsbuf, xg2);
    k_proj_naive<64,false><<<dim3(NN), dim3(64), 0, stream>>>(x, zsbuf, xg2, ne1, uwp, ubp, st, rbuf, d_out, rbuf);
}